// Round 1
// baseline (2858.673 us; speedup 1.0000x reference)
//
#include <hip/hip_runtime.h>
#include <hip/hip_bf16.h>
#include <cmath>

typedef float f32x4 __attribute__((ext_vector_type(4)));
typedef short bf16x8 __attribute__((ext_vector_type(8)));

static __device__ __forceinline__ float bf2f(unsigned short u){
  return __uint_as_float(((unsigned)u) << 16);
}
static __device__ __forceinline__ unsigned short f2bf(float f){
  unsigned u = __float_as_uint(f);
  unsigned r = u + 0x7FFFu + ((u >> 16) & 1u);
  return (unsigned short)(r >> 16);
}

// ---------------- weight convert+transpose: out[n][k] = bf16(in[k][n]) ----------------
__global__ void wconv_kernel(const float* __restrict__ in, unsigned short* __restrict__ out,
                             int K, int N){
  int idx = blockIdx.x * 256 + threadIdx.x;
  if (idx < K * N){
    int n = idx / K, k = idx - n * K;
    out[idx] = f2bf(in[(size_t)k * N + n]);
  }
}

// ---------------- LayerNorm (+optional shift+window-partition gather) ----------------
// MODE 0: read x (natural order), write w_win row t (window order), gather via shifted coords
// MODE 1: read x2 (natural), write ln2 (natural)
template<int MODE>
__global__ __launch_bounds__(256) void ln_kernel(const float* __restrict__ in,
                                                 const float* __restrict__ g,
                                                 const float* __restrict__ bta,
                                                 unsigned short* __restrict__ out){
  int wave = threadIdx.x >> 6, lane = threadIdx.x & 63;
  int row = blockIdx.x * 4 + wave;          // < 43904
  size_t srow;
  if (MODE == 0){
    int win = row / 343, n = row - win * 343;
    int b = win >> 6, w64 = win & 63;
    int zw = w64 >> 5, xw = (w64 >> 3) & 3, yw = w64 & 7;
    int i0 = n / 49, nr = n - i0 * 49, i1 = nr / 7, i2 = nr - i1 * 7;
    int zs = zw * 7 + i0 + 3; if (zs >= 14) zs -= 14;
    int xs = xw * 7 + i1 + 3; if (xs >= 28) xs -= 28;
    int ys = yw * 7 + i2 + 3; if (ys >= 56) ys -= 56;
    srow = (size_t)b * 21952 + zs * 1568 + xs * 56 + ys;
  } else {
    srow = (size_t)row;
  }
  const float* p = in + srow * 384;
  float v[6]; float s = 0.f;
  #pragma unroll
  for (int i = 0; i < 6; i++){ v[i] = p[lane + i * 64]; s += v[i]; }
  #pragma unroll
  for (int off = 32; off >= 1; off >>= 1) s += __shfl_xor(s, off);
  float mean = s * (1.f / 384.f);
  float vs = 0.f;
  #pragma unroll
  for (int i = 0; i < 6; i++){ float d = v[i] - mean; vs += d * d; }
  #pragma unroll
  for (int off = 32; off >= 1; off >>= 1) vs += __shfl_xor(vs, off);
  float rstd = rsqrtf(vs * (1.f / 384.f) + 1e-5f);
  unsigned short* o = out + (size_t)row * 384;
  #pragma unroll
  for (int i = 0; i < 6; i++){
    int c = lane + i * 64;
    o[c] = f2bf((v[i] - mean) * rstd * g[c] + bta[c]);
  }
}

// ---------------- GEMM: C[M,N] = A[M,K] @ Bt[N,K]^T, fused epilogues ----------------
// EPI 0: +bias, scale cols<384 by 1/sqrt(32), store bf16 (QKV)
// EPI 1: +bias, window-reverse+roll scatter, += resid(x), store f32 (PROJ -> x2)
// EPI 2: +bias, exact GELU, store bf16 (FC1 -> hidden)
// EPI 3: +bias, += resid(x2) row-major, store f32 (FC2 -> out)
template<int EPI>
__global__ __launch_bounds__(256) void gemm_bt(
    const unsigned short* __restrict__ A,
    const unsigned short* __restrict__ Bt,
    const float* __restrict__ bias,
    const float* __restrict__ resid,
    void* __restrict__ outp,
    int K, int ldc){
  __shared__ unsigned short As[128 * 32];
  __shared__ unsigned short Bs[128 * 32];
  const int tid = threadIdx.x, lane = tid & 63, wave = tid >> 6;
  const int r0 = blockIdx.x * 128, c0 = blockIdx.y * 128;
  const int wr = (wave >> 1) * 64, wc = (wave & 1) * 64;
  f32x4 acc[4][4];
  #pragma unroll
  for (int mi = 0; mi < 4; mi++)
    #pragma unroll
    for (int ni = 0; ni < 4; ni++) acc[mi][ni] = f32x4{0.f, 0.f, 0.f, 0.f};

  const int flat = tid * 8;                 // elems within 128x32 tile
  const int rowA = flat >> 5, kk = flat & 31;
  const unsigned short* Ag = A + (size_t)(r0 + rowA) * K + kk;
  const unsigned short* Bg = Bt + (size_t)(c0 + rowA) * K + kk;
  const int aoff = (wr + (lane & 15)) * 32 + (lane >> 4) * 8;
  const int boff = (wc + (lane & 15)) * 32 + (lane >> 4) * 8;

  for (int k0 = 0; k0 < K; k0 += 32){
    int4 a0 = *(const int4*)(Ag + k0);
    int4 a1 = *(const int4*)(Ag + (size_t)64 * K + k0);
    int4 b0 = *(const int4*)(Bg + k0);
    int4 b1 = *(const int4*)(Bg + (size_t)64 * K + k0);
    __syncthreads();
    *(int4*)(&As[flat]) = a0; *(int4*)(&As[flat + 2048]) = a1;
    *(int4*)(&Bs[flat]) = b0; *(int4*)(&Bs[flat + 2048]) = b1;
    __syncthreads();
    bf16x8 af[4], bfr[4];
    #pragma unroll
    for (int mi = 0; mi < 4; mi++) af[mi] = *(const bf16x8*)(&As[aoff + mi * 512]);
    #pragma unroll
    for (int ni = 0; ni < 4; ni++) bfr[ni] = *(const bf16x8*)(&Bs[boff + ni * 512]);
    #pragma unroll
    for (int mi = 0; mi < 4; mi++)
      #pragma unroll
      for (int ni = 0; ni < 4; ni++)
        acc[mi][ni] = __builtin_amdgcn_mfma_f32_16x16x32_bf16(af[mi], bfr[ni], acc[mi][ni], 0, 0, 0);
  }

  #pragma unroll
  for (int mi = 0; mi < 4; mi++){
    #pragma unroll
    for (int ni = 0; ni < 4; ni++){
      #pragma unroll
      for (int j = 0; j < 4; j++){
        int row = r0 + wr + mi * 16 + ((lane >> 4) << 2) + j;
        int col = c0 + wc + ni * 16 + (lane & 15);
        float val = acc[mi][ni][j] + bias[col];
        if (EPI == 0){
          if (col < 384) val *= 0.17677669529663687f;
          ((unsigned short*)outp)[(size_t)row * ldc + col] = f2bf(val);
        } else if (EPI == 1){
          int win = row / 343, n_ = row - win * 343;
          int b = win >> 6, w64 = win & 63;
          int zw = w64 >> 5, xw = (w64 >> 3) & 3, yw = w64 & 7;
          int i0 = n_ / 49, nr = n_ - i0 * 49, i1 = nr / 7, i2 = nr - i1 * 7;
          int zf = zw * 7 + i0 + 3; if (zf >= 14) zf -= 14;
          int xf = xw * 7 + i1 + 3; if (xf >= 28) xf -= 28;
          int yf = yw * 7 + i2 + 3; if (yf >= 56) yf -= 56;
          size_t dst = ((size_t)b * 21952 + zf * 1568 + xf * 56 + yf) * 384 + col;
          ((float*)outp)[dst] = resid[dst] + val;
        } else if (EPI == 2){
          val = 0.5f * val * (1.0f + erff(val * 0.70710678118654752f));
          ((unsigned short*)outp)[(size_t)row * ldc + col] = f2bf(val);
        } else {
          ((float*)outp)[(size_t)row * ldc + col] =
              resid[(size_t)row * ldc + col] + val;
        }
      }
    }
  }
}

// ---------------- attention: one block per (window, head) ----------------
__global__ __launch_bounds__(256) void attn_kernel(
    const unsigned short* __restrict__ qkv,
    const float* __restrict__ rel_tbl,
    unsigned short* __restrict__ out){
  __shared__ unsigned short k_s[343 * 34];
  __shared__ unsigned short v_s[343 * 34];
  __shared__ float rel_s[2197];
  __shared__ float p_s[4][344];
  __shared__ unsigned char cnt_s[344];
  const int bid = blockIdx.x;
  const int win = bid / 12, h = bid - win * 12;
  const int tid = threadIdx.x, wave = tid >> 6, lane = tid & 63;
  const int w64 = win & 63, zw = w64 >> 5, xw = (w64 >> 3) & 3, yw = w64 & 7;

  for (int i = tid; i < 2197; i += 256) rel_s[i] = rel_tbl[i * 12 + h];
  const unsigned short* qbase = qkv + (size_t)win * 343 * 1152 + h * 32;
  for (int i = tid; i < 5488; i += 256){       // 343*16 uint chunks (2 bf16 each)
    int n = i >> 4, c2 = (i & 15) << 1;
    const unsigned short* src = qbase + (size_t)n * 1152 + c2;
    *(unsigned*)(&k_s[n * 34 + c2]) = *(const unsigned*)(src + 384);
    *(unsigned*)(&v_s[n * 34 + c2]) = *(const unsigned*)(src + 768);
  }
  for (int n = tid; n < 343; n += 256){
    int i0 = n / 49, nr = n - i0 * 49, i1 = nr / 7, i2 = nr - i1 * 7;
    int z = zw * 7 + i0, x = xw * 7 + i1, y = yw * 7 + i2;
    int az = (z < 7) ? 0 : ((z < 11) ? 1 : 2);
    int ax = (x < 21) ? 0 : ((x < 25) ? 1 : 2);
    int ay = (y < 49) ? 0 : ((y < 53) ? 1 : 2);
    cnt_s[n] = (unsigned char)(az * 9 + ax * 3 + ay);
  }
  __syncthreads();

  const int d = lane & 31, half = lane >> 5;
  for (int r = wave; r < 343; r += 4){
    const unsigned short* qp = qbase + (size_t)r * 1152;
    float q[32];
    #pragma unroll
    for (int i = 0; i < 16; i++){
      unsigned u = *(const unsigned*)(qp + 2 * i);
      q[2 * i]     = __uint_as_float(u << 16);
      q[2 * i + 1] = __uint_as_float(u & 0xffff0000u);
    }
    int i0r = r / 49, rr = r - i0r * 49, i1r = rr / 7, i2r = rr - i1r * 7;
    int cr = cnt_s[r];
    float sc[6];
    float mx = -1e30f;
    #pragma unroll
    for (int it = 0; it < 6; it++){
      int m = lane + it * 64;
      float s = -1e30f;
      if (m < 343){
        float a = 0.f;
        const unsigned short* kp = &k_s[m * 34];
        #pragma unroll
        for (int i = 0; i < 16; i++){
          unsigned u = *(const unsigned*)(kp + 2 * i);
          a += q[2 * i]     * __uint_as_float(u << 16);
          a += q[2 * i + 1] * __uint_as_float(u & 0xffff0000u);
        }
        int i0m = m / 49, rm = m - i0m * 49, i1m = rm / 7, i2m = rm - i1m * 7;
        int idx = 13 * (i0r - i0m + 6) + (i1r - i1m + 6) + (i2r - i2m);
        if (idx < 0) idx += 2197;
        a += rel_s[idx];
        if (cnt_s[m] != cr) a -= 100.f;
        s = a;
      }
      sc[it] = s;
      mx = fmaxf(mx, s);
    }
    #pragma unroll
    for (int off = 32; off >= 1; off >>= 1) mx = fmaxf(mx, __shfl_xor(mx, off));
    float sum = 0.f;
    #pragma unroll
    for (int it = 0; it < 6; it++){
      float e = (lane + it * 64 < 343) ? __expf(sc[it] - mx) : 0.f;
      sc[it] = e; sum += e;
    }
    #pragma unroll
    for (int off = 32; off >= 1; off >>= 1) sum += __shfl_xor(sum, off);
    float inv = 1.0f / sum;
    // ensure prior-row PV reads of p_s are complete before overwrite (in-wave LDS order)
    asm volatile("s_waitcnt lgkmcnt(0)" ::: "memory");
    #pragma unroll
    for (int it = 0; it < 6; it++){
      int m = lane + it * 64;
      if (m < 343) p_s[wave][m] = sc[it] * inv;
    }
    asm volatile("s_waitcnt lgkmcnt(0)" ::: "memory");
    float o = 0.f;
    for (int k2 = half; k2 < 343; k2 += 2)
      o += p_s[wave][k2] * bf2f(v_s[k2 * 34 + d]);
    o += __shfl_xor(o, 32);
    if (lane < 32)
      out[((size_t)win * 343 + r) * 384 + h * 32 + d] = f2bf(o);
  }
}

// ---------------- host launcher ----------------
extern "C" void kernel_launch(void* const* d_in, const int* in_sizes, int n_in,
                              void* d_out, int out_size, void* d_ws, size_t ws_size,
                              hipStream_t stream){
  const float* x      = (const float*)d_in[0];
  const float* n1g    = (const float*)d_in[1];
  const float* n1b    = (const float*)d_in[2];
  const float* qkv_w  = (const float*)d_in[3];
  const float* qkv_b  = (const float*)d_in[4];
  const float* proj_w = (const float*)d_in[5];
  const float* proj_b = (const float*)d_in[6];
  const float* rel    = (const float*)d_in[7];
  const float* n2g    = (const float*)d_in[8];
  const float* n2b    = (const float*)d_in[9];
  const float* fc1_w  = (const float*)d_in[10];
  const float* fc1_b  = (const float*)d_in[11];
  const float* fc2_w  = (const float*)d_in[12];
  const float* fc2_b  = (const float*)d_in[13];
  float* out = (float*)d_out;

  char* ws = (char*)d_ws;
  // T = 43904 tokens. Region plan (bytes):
  // [0, 33718272)          w_win bf16 [T][384]   -- reused (with qkv) as hidden bf16 [T][1536]
  // [33718272, 134873088)  qkv bf16 [T][1152]
  // [134873088, 168591360) attn_out bf16 [T][384] -- reused as ln2 bf16
  // [168591360, 236027904) x2 f32 [T][384]
  // [236027904, ...)       bf16 transposed weights
  unsigned short* w_win  = (unsigned short*)(ws + 0);
  unsigned short* qkv    = (unsigned short*)(ws + 33718272ull);
  unsigned short* hidden = (unsigned short*)(ws + 0);
  unsigned short* att    = (unsigned short*)(ws + 134873088ull);
  unsigned short* ln2    = att;
  float*          x2     = (float*)(ws + 168591360ull);
  unsigned short* wt_qkv = (unsigned short*)(ws + 236027904ull);
  unsigned short* wt_prj = (unsigned short*)(ws + 236912640ull);
  unsigned short* wt_fc1 = (unsigned short*)(ws + 237207552ull);
  unsigned short* wt_fc2 = (unsigned short*)(ws + 238387200ull);

  wconv_kernel<<<(442368 + 255) / 256, 256, 0, stream>>>(qkv_w, wt_qkv, 384, 1152);
  wconv_kernel<<<(147456 + 255) / 256, 256, 0, stream>>>(proj_w, wt_prj, 384, 384);
  wconv_kernel<<<(589824 + 255) / 256, 256, 0, stream>>>(fc1_w, wt_fc1, 384, 1536);
  wconv_kernel<<<(589824 + 255) / 256, 256, 0, stream>>>(fc2_w, wt_fc2, 1536, 384);

  ln_kernel<0><<<10976, 256, 0, stream>>>(x, n1g, n1b, w_win);
  gemm_bt<0><<<dim3(343, 9), 256, 0, stream>>>(w_win, wt_qkv, qkv_b, nullptr, qkv, 384, 1152);
  attn_kernel<<<1536, 256, 0, stream>>>(qkv, rel, att);
  gemm_bt<1><<<dim3(343, 3), 256, 0, stream>>>(att, wt_prj, proj_b, x, x2, 384, 384);
  ln_kernel<1><<<10976, 256, 0, stream>>>(x2, n2g, n2b, ln2);
  gemm_bt<2><<<dim3(343, 12), 256, 0, stream>>>(ln2, wt_fc1, fc1_b, nullptr, hidden, 384, 1536);
  gemm_bt<3><<<dim3(343, 3), 256, 0, stream>>>(hidden, wt_fc2, fc2_b, x2, out, 1536, 384);
}

// Round 2
// 653.456 us; speedup vs baseline: 4.3747x; 4.3747x over previous
//
#include <hip/hip_runtime.h>
#include <hip/hip_bf16.h>
#include <cmath>

typedef float f32x4 __attribute__((ext_vector_type(4)));
typedef float f32x16 __attribute__((ext_vector_type(16)));
typedef short bf16x8 __attribute__((ext_vector_type(8)));

static __device__ __forceinline__ float bf2f(unsigned short u){
  return __uint_as_float(((unsigned)u) << 16);
}
static __device__ __forceinline__ unsigned short f2bf(float f){
  unsigned u = __float_as_uint(f);
  unsigned r = u + 0x7FFFu + ((u >> 16) & 1u);
  return (unsigned short)(r >> 16);
}
static __device__ __forceinline__ f32x16 zero16(){
  f32x16 z;
  #pragma unroll
  for (int i = 0; i < 16; i++) z[i] = 0.f;
  return z;
}

// ---------------- weight convert+transpose: out[n][k] = bf16(in[k][n]) ----------------
__global__ void wconv_kernel(const float* __restrict__ in, unsigned short* __restrict__ out,
                             int K, int N){
  int idx = blockIdx.x * 256 + threadIdx.x;
  if (idx < K * N){
    int n = idx / K, k = idx - n * K;
    out[idx] = f2bf(in[(size_t)k * N + n]);
  }
}

// ---------------- bias prep: bias12[h][q][m] bf16, m>=343 -> -1e30 ----------------
__global__ void biasprep_kernel(const float* __restrict__ rel, unsigned short* __restrict__ bias12){
  int p = blockIdx.x * 256 + threadIdx.x;
  if (p >= 743424) return;              // 12 * 352 * 176
  int h = p / 61952;                    // 352*176
  int rem = p - h * 61952;
  int q = rem / 176;
  int m2 = (rem - q * 176) * 2;
  int qi0 = q / 49, qr = q - qi0 * 49, qi1 = qr / 7, qi2 = qr - qi1 * 7;
  unsigned v[2];
  #pragma unroll
  for (int j = 0; j < 2; j++){
    int m = m2 + j;
    float val;
    if (m >= 343) val = -1e30f;
    else {
      int mi0 = m / 49, mr = m - mi0 * 49, mi1 = mr / 7, mi2 = mr - mi1 * 7;
      int idx = 13 * (qi0 - mi0 + 6) + (qi1 - mi1 + 6) + (qi2 - mi2);
      if (idx < 0) idx += 2197;
      val = rel[idx * 12 + h];
    }
    v[j] = f2bf(val);
  }
  *(unsigned*)(&bias12[(size_t)h * 123904 + q * 352 + m2]) = v[0] | (v[1] << 16);
}

// ---------------- LayerNorm (+optional shift+window-partition gather) ----------------
template<int MODE>
__global__ __launch_bounds__(256) void ln_kernel(const float* __restrict__ in,
                                                 const float* __restrict__ g,
                                                 const float* __restrict__ bta,
                                                 unsigned short* __restrict__ out){
  int wave = threadIdx.x >> 6, lane = threadIdx.x & 63;
  int row = blockIdx.x * 4 + wave;          // < 43904
  size_t srow;
  if (MODE == 0){
    int win = row / 343, n = row - win * 343;
    int b = win >> 6, w64 = win & 63;
    int zw = w64 >> 5, xw = (w64 >> 3) & 3, yw = w64 & 7;
    int i0 = n / 49, nr = n - i0 * 49, i1 = nr / 7, i2 = nr - i1 * 7;
    int zs = zw * 7 + i0 + 3; if (zs >= 14) zs -= 14;
    int xs = xw * 7 + i1 + 3; if (xs >= 28) xs -= 28;
    int ys = yw * 7 + i2 + 3; if (ys >= 56) ys -= 56;
    srow = (size_t)b * 21952 + zs * 1568 + xs * 56 + ys;
  } else {
    srow = (size_t)row;
  }
  const float* p = in + srow * 384;
  float v[6]; float s = 0.f;
  #pragma unroll
  for (int i = 0; i < 6; i++){ v[i] = p[lane + i * 64]; s += v[i]; }
  #pragma unroll
  for (int off = 32; off >= 1; off >>= 1) s += __shfl_xor(s, off);
  float mean = s * (1.f / 384.f);
  float vs = 0.f;
  #pragma unroll
  for (int i = 0; i < 6; i++){ float d = v[i] - mean; vs += d * d; }
  #pragma unroll
  for (int off = 32; off >= 1; off >>= 1) vs += __shfl_xor(vs, off);
  float rstd = rsqrtf(vs * (1.f / 384.f) + 1e-5f);
  unsigned short* o = out + (size_t)row * 384;
  #pragma unroll
  for (int i = 0; i < 6; i++){
    int c = lane + i * 64;
    o[c] = f2bf((v[i] - mean) * rstd * g[c] + bta[c]);
  }
}

// ---------------- GEMM: C[M,N] = A[M,K] @ Bt[N,K]^T, fused epilogues ----------------
template<int EPI>
__global__ __launch_bounds__(256) void gemm_bt(
    const unsigned short* __restrict__ A,
    const unsigned short* __restrict__ Bt,
    const float* __restrict__ bias,
    const float* __restrict__ resid,
    void* __restrict__ outp,
    int K, int ldc){
  __shared__ unsigned short As[128 * 32];
  __shared__ unsigned short Bs[128 * 32];
  const int tid = threadIdx.x, lane = tid & 63, wave = tid >> 6;
  const int r0 = blockIdx.x * 128, c0 = blockIdx.y * 128;
  const int wr = (wave >> 1) * 64, wc = (wave & 1) * 64;
  f32x4 acc[4][4];
  #pragma unroll
  for (int mi = 0; mi < 4; mi++)
    #pragma unroll
    for (int ni = 0; ni < 4; ni++) acc[mi][ni] = f32x4{0.f, 0.f, 0.f, 0.f};

  const int flat = tid * 8;                 // elems within 128x32 tile
  const int rowA = flat >> 5, kk = flat & 31;
  const unsigned short* Ag = A + (size_t)(r0 + rowA) * K + kk;
  const unsigned short* Bg = Bt + (size_t)(c0 + rowA) * K + kk;
  const int aoff = (wr + (lane & 15)) * 32 + (lane >> 4) * 8;
  const int boff = (wc + (lane & 15)) * 32 + (lane >> 4) * 8;

  for (int k0 = 0; k0 < K; k0 += 32){
    int4 a0 = *(const int4*)(Ag + k0);
    int4 a1 = *(const int4*)(Ag + (size_t)64 * K + k0);
    int4 b0 = *(const int4*)(Bg + k0);
    int4 b1 = *(const int4*)(Bg + (size_t)64 * K + k0);
    __syncthreads();
    *(int4*)(&As[flat]) = a0; *(int4*)(&As[flat + 2048]) = a1;
    *(int4*)(&Bs[flat]) = b0; *(int4*)(&Bs[flat + 2048]) = b1;
    __syncthreads();
    bf16x8 af[4], bfr[4];
    #pragma unroll
    for (int mi = 0; mi < 4; mi++) af[mi] = *(const bf16x8*)(&As[aoff + mi * 512]);
    #pragma unroll
    for (int ni = 0; ni < 4; ni++) bfr[ni] = *(const bf16x8*)(&Bs[boff + ni * 512]);
    #pragma unroll
    for (int mi = 0; mi < 4; mi++)
      #pragma unroll
      for (int ni = 0; ni < 4; ni++)
        acc[mi][ni] = __builtin_amdgcn_mfma_f32_16x16x32_bf16(af[mi], bfr[ni], acc[mi][ni], 0, 0, 0);
  }

  #pragma unroll
  for (int mi = 0; mi < 4; mi++){
    #pragma unroll
    for (int ni = 0; ni < 4; ni++){
      #pragma unroll
      for (int j = 0; j < 4; j++){
        int row = r0 + wr + mi * 16 + ((lane >> 4) << 2) + j;
        int col = c0 + wc + ni * 16 + (lane & 15);
        float val = acc[mi][ni][j] + bias[col];
        if (EPI == 0){
          if (col < 384) val *= 0.17677669529663687f;
          ((unsigned short*)outp)[(size_t)row * ldc + col] = f2bf(val);
        } else if (EPI == 1){
          int win = row / 343, n_ = row - win * 343;
          int b = win >> 6, w64 = win & 63;
          int zw = w64 >> 5, xw = (w64 >> 3) & 3, yw = w64 & 7;
          int i0 = n_ / 49, nr = n_ - i0 * 49, i1 = nr / 7, i2 = nr - i1 * 7;
          int zf = zw * 7 + i0 + 3; if (zf >= 14) zf -= 14;
          int xf = xw * 7 + i1 + 3; if (xf >= 28) xf -= 28;
          int yf = yw * 7 + i2 + 3; if (yf >= 56) yf -= 56;
          size_t dst = ((size_t)b * 21952 + zf * 1568 + xf * 56 + yf) * 384 + col;
          ((float*)outp)[dst] = resid[dst] + val;
        } else if (EPI == 2){
          val = 0.5f * val * (1.0f + erff(val * 0.70710678118654752f));
          ((unsigned short*)outp)[(size_t)row * ldc + col] = f2bf(val);
        } else {
          ((float*)outp)[(size_t)row * ldc + col] =
              resid[(size_t)row * ldc + col] + val;
        }
      }
    }
  }
}

// ---------------- MFMA attention: one block per (window, head), 4 waves ----------------
// S^T = mfma(A=K, B=Q) per 32-m tile; softmax in C-layout (no max-sub: scores ~ +-3);
// P via per-wave LDS tile; V staged transposed (VT[d][m]) so PV B-frag is contiguous.
__global__ __launch_bounds__(256) void attn2_kernel(
    const unsigned short* __restrict__ qkv,
    const unsigned short* __restrict__ bias12,
    unsigned short* __restrict__ out){
  __shared__ unsigned short Ks[352 * 32];        // [m][32d], 16B-chunk xor-swizzled
  __shared__ unsigned short VT[32 * 384];        // [d][384m-pad], 8-elem-chunk xor-swizzled
  __shared__ unsigned short Ps[4][32 * 40];      // per-wave P tile [q][40m]
  __shared__ float inv_s[4][32];
  __shared__ unsigned char cnt_s[352];
  const int bid = blockIdx.x;
  const int win = bid / 12, h = bid - win * 12;
  const int tid = threadIdx.x, wave = tid >> 6, lane = tid & 63;
  const int hh = lane >> 5, ln = lane & 31;
  const int w64 = win & 63, zw = w64 >> 5, xw = (w64 >> 3) & 3, yw = w64 & 7;
  const bool masked = (zw == 1) || (xw == 3) || (yw == 7);

  // ---- stage K (natural+swizzle) and V (transposed+swizzle) ----
  for (int task = tid; task < 2816; task += 256){
    if (task < 1408){
      int m = task >> 2, c = task & 3;
      const unsigned short* src = qkv + (size_t)(win * 343 + m) * 1152 + 384 + h * 32 + c * 8;
      int4 v = *(const int4*)src;
      int cp = c ^ ((m >> 1) & 3);
      *(int4*)(&Ks[m * 32 + cp * 8]) = v;
    } else {
      int t2 = task - 1408;
      int m = t2 >> 2, dg = t2 & 3;
      const unsigned short* src = qkv + (size_t)(win * 343 + m) * 1152 + 768 + h * 32 + dg * 8;
      int4 v = *(const int4*)src;
      union { int4 i; unsigned short u[8]; } cv; cv.i = v;
      int cc = m >> 3, mlow = m & 7;
      #pragma unroll
      for (int j = 0; j < 8; j++){
        int d = dg * 8 + j;
        int ccs = (cc & ~7) | ((cc & 7) ^ (d & 7));
        VT[d * 384 + ccs * 8 + mlow] = cv.u[j];
      }
    }
  }
  for (int n = tid; n < 352; n += 256){
    int i0 = n / 49, nr = n - i0 * 49, i1 = nr / 7, i2 = nr - i1 * 7;
    int z = zw * 7 + i0, x = xw * 7 + i1, y = yw * 7 + i2;
    int az = (z < 7) ? 0 : ((z < 11) ? 1 : 2);
    int ax = (x < 21) ? 0 : ((x < 25) ? 1 : 2);
    int ay = (y < 49) ? 0 : ((y < 53) ? 1 : 2);
    cnt_s[n] = (unsigned char)(az * 9 + ax * 3 + ay);
  }
  __syncthreads();

  const unsigned short* bias_h = bias12 + (size_t)h * 123904;
  const int kkey = (ln >> 1) & 3;                 // Ks swizzle key (t-independent)

  for (int qt = wave; qt < 11; qt += 4){
    const int q0 = qt * 32;
    const int q_lane = q0 + ln;
    const size_t qrow = (size_t)(win * 343 + q_lane) * 1152 + h * 32;
    bf16x8 bq0 = *(const bf16x8*)(qkv + qrow + hh * 8);
    bf16x8 bq1 = *(const bf16x8*)(qkv + qrow + 16 + hh * 8);
    const int cq = masked ? (int)cnt_s[q_lane] : 0;
    const unsigned short* bias_q = bias_h + (size_t)q_lane * 352;

    f32x16 o = zero16();
    float sum = 0.f;
    #pragma unroll
    for (int t = 0; t < 11; t++){
      const int mb = t * 32;
      // QK^T (swapped): S^T tile, col=q (lane&31), row=m
      bf16x8 ka0 = *(const bf16x8*)(&Ks[(mb + ln) * 32 + ((0 + hh) ^ kkey) * 8]);
      bf16x8 ka1 = *(const bf16x8*)(&Ks[(mb + ln) * 32 + ((2 + hh) ^ kkey) * 8]);
      f32x16 acc = zero16();
      acc = __builtin_amdgcn_mfma_f32_32x32x16_bf16(ka0, bq0, acc, 0, 0, 0);
      acc = __builtin_amdgcn_mfma_f32_32x32x16_bf16(ka1, bq1, acc, 0, 0, 0);
      // bias (+mask) + exp + sum
      ushort4 bl[4];
      #pragma unroll
      for (int g = 0; g < 4; g++)
        bl[g] = *(const ushort4*)(bias_q + mb + g * 8 + hh * 4);
      float p[16];
      #pragma unroll
      for (int g = 0; g < 4; g++){
        const unsigned short* bu = (const unsigned short*)&bl[g];
        #pragma unroll
        for (int i = 0; i < 4; i++){
          int r = g * 4 + i;
          float s = acc[r] + bf2f(bu[i]);
          if (masked){
            int m = mb + i + 8 * g + 4 * hh;
            if ((int)cnt_s[m] != cq) s -= 100.f;
          }
          float e = __expf(s);
          sum += e;
          p[r] = e;
        }
      }
      // pack P -> per-wave LDS tile [q][40]
      #pragma unroll
      for (int g = 0; g < 4; g++){
        uint2 pk;
        pk.x = (unsigned)f2bf(p[g * 4 + 0]) | ((unsigned)f2bf(p[g * 4 + 1]) << 16);
        pk.y = (unsigned)f2bf(p[g * 4 + 2]) | ((unsigned)f2bf(p[g * 4 + 3]) << 16);
        *(uint2*)(&Ps[wave][ln * 40 + 8 * g + 4 * hh]) = pk;
      }
      // PV: A=P (row q), B=V^T rows (col d)
      bf16x8 pa0 = *(const bf16x8*)(&Ps[wave][ln * 40 + 8 * hh]);
      bf16x8 pa1 = *(const bf16x8*)(&Ps[wave][ln * 40 + 16 + 8 * hh]);
      int cc0 = 4 * t + hh, cc1 = 4 * t + 2 + hh;
      int cs0 = (cc0 & ~7) | ((cc0 & 7) ^ (ln & 7));
      int cs1 = (cc1 & ~7) | ((cc1 & 7) ^ (ln & 7));
      bf16x8 bv0 = *(const bf16x8*)(&VT[ln * 384 + cs0 * 8]);
      bf16x8 bv1 = *(const bf16x8*)(&VT[ln * 384 + cs1 * 8]);
      o = __builtin_amdgcn_mfma_f32_32x32x16_bf16(pa0, bv0, o, 0, 0, 0);
      o = __builtin_amdgcn_mfma_f32_32x32x16_bf16(pa1, bv1, o, 0, 0, 0);
    }
    sum += __shfl_xor(sum, 32);
    float inv = 1.f / sum;
    if (lane < 32) inv_s[wave][lane] = inv;
    // epilogue: scale by 1/sum (per output row), store bf16
    #pragma unroll
    for (int r = 0; r < 16; r++){
      int qloc = (r & 3) + 8 * (r >> 2) + 4 * hh;
      int qg = q0 + qloc;
      if (qg < 343){
        float val = o[r] * inv_s[wave][qloc];
        out[((size_t)win * 343 + qg) * 384 + h * 32 + ln] = f2bf(val);
      }
    }
  }
}

// ---------------- host launcher ----------------
extern "C" void kernel_launch(void* const* d_in, const int* in_sizes, int n_in,
                              void* d_out, int out_size, void* d_ws, size_t ws_size,
                              hipStream_t stream){
  const float* x      = (const float*)d_in[0];
  const float* n1g    = (const float*)d_in[1];
  const float* n1b    = (const float*)d_in[2];
  const float* qkv_w  = (const float*)d_in[3];
  const float* qkv_b  = (const float*)d_in[4];
  const float* proj_w = (const float*)d_in[5];
  const float* proj_b = (const float*)d_in[6];
  const float* rel    = (const float*)d_in[7];
  const float* n2g    = (const float*)d_in[8];
  const float* n2b    = (const float*)d_in[9];
  const float* fc1_w  = (const float*)d_in[10];
  const float* fc1_b  = (const float*)d_in[11];
  const float* fc2_w  = (const float*)d_in[12];
  const float* fc2_b  = (const float*)d_in[13];
  float* out = (float*)d_out;

  char* ws = (char*)d_ws;
  // T = 43904 tokens. Region plan (bytes):
  // [0, 33718272)          w_win bf16 [T][384]   -- reused (with qkv) as hidden bf16 [T][1536]
  // [33718272, 134873088)  qkv bf16 [T][1152]
  // [134873088, 168591360) attn_out bf16 [T][384] -- reused as ln2 bf16
  // [168591360, 236027904) x2 f32 [T][384]        -- bias12 bf16 (5.95MB) lives here pre-proj
  // [236027904, ...)       bf16 transposed weights
  unsigned short* w_win  = (unsigned short*)(ws + 0);
  unsigned short* qkv    = (unsigned short*)(ws + 33718272ull);
  unsigned short* hidden = (unsigned short*)(ws + 0);
  unsigned short* att    = (unsigned short*)(ws + 134873088ull);
  unsigned short* ln2    = att;
  float*          x2     = (float*)(ws + 168591360ull);
  unsigned short* bias12 = (unsigned short*)(ws + 168591360ull);  // overwritten by x2 after attn
  unsigned short* wt_qkv = (unsigned short*)(ws + 236027904ull);
  unsigned short* wt_prj = (unsigned short*)(ws + 236912640ull);
  unsigned short* wt_fc1 = (unsigned short*)(ws + 237207552ull);
  unsigned short* wt_fc2 = (unsigned short*)(ws + 238387200ull);

  wconv_kernel<<<(442368 + 255) / 256, 256, 0, stream>>>(qkv_w, wt_qkv, 384, 1152);
  wconv_kernel<<<(147456 + 255) / 256, 256, 0, stream>>>(proj_w, wt_prj, 384, 384);
  wconv_kernel<<<(589824 + 255) / 256, 256, 0, stream>>>(fc1_w, wt_fc1, 384, 1536);
  wconv_kernel<<<(589824 + 255) / 256, 256, 0, stream>>>(fc2_w, wt_fc2, 1536, 384);
  biasprep_kernel<<<2904, 256, 0, stream>>>(rel, bias12);

  ln_kernel<0><<<10976, 256, 0, stream>>>(x, n1g, n1b, w_win);
  gemm_bt<0><<<dim3(343, 9), 256, 0, stream>>>(w_win, wt_qkv, qkv_b, nullptr, qkv, 384, 1152);
  attn2_kernel<<<1536, 256, 0, stream>>>(qkv, bias12, att);
  gemm_bt<1><<<dim3(343, 3), 256, 0, stream>>>(att, wt_prj, proj_b, x, x2, 384, 384);
  ln_kernel<1><<<10976, 256, 0, stream>>>(x2, n2g, n2b, ln2);
  gemm_bt<2><<<dim3(343, 12), 256, 0, stream>>>(ln2, wt_fc1, fc1_b, nullptr, hidden, 384, 1536);
  gemm_bt<3><<<dim3(343, 3), 256, 0, stream>>>(hidden, wt_fc2, fc2_b, x2, out, 1536, 384);
}

// Round 4
// 560.370 us; speedup vs baseline: 5.1014x; 1.1661x over previous
//
#include <hip/hip_runtime.h>
#include <hip/hip_bf16.h>
#include <cmath>

typedef float f32x4 __attribute__((ext_vector_type(4)));
typedef float f32x16 __attribute__((ext_vector_type(16)));
typedef short bf16x8 __attribute__((ext_vector_type(8)));
typedef const __attribute__((address_space(1))) unsigned int* gas_t;
typedef __attribute__((address_space(3))) unsigned int* las_t;

#define GLOAD16(g, l) __builtin_amdgcn_global_load_lds((gas_t)(const void*)(g), (las_t)(void*)(l), 16, 0, 0)

#define LOG2E 1.4426950408889634f
#define MASKC (-144.2695040888963f)
#define SL2E  (0.17677669529663687f * 1.4426950408889634f)

static __device__ __forceinline__ float bf2f(unsigned short u){
  return __uint_as_float(((unsigned)u) << 16);
}
static __device__ __forceinline__ unsigned short f2bf(float f){
  unsigned u = __float_as_uint(f);
  unsigned r = u + 0x7FFFu + ((u >> 16) & 1u);
  return (unsigned short)(r >> 16);
}
static __device__ __forceinline__ unsigned packbf(float a, float b){
  union { __hip_bfloat162 h; unsigned u; } cv;
  cv.h = __float22bfloat162_rn(make_float2(a, b));
  return cv.u;
}
static __device__ __forceinline__ f32x16 zero16(){
  f32x16 z;
  #pragma unroll
  for (int i = 0; i < 16; i++) z[i] = 0.f;
  return z;
}

// ---------------- zero pad slots (tile t=10, m=320..351 incl. pads 343..351) of qs2/ks2/vt2 ----------------
// Makes attention input fully written-this-call: no stale-workspace NaN/Inf can leak in.
__global__ __launch_bounds__(256) void padzero_kernel(unsigned short* __restrict__ qs2,
                                                      unsigned short* __restrict__ ks2,
                                                      unsigned short* __restrict__ vt2){
  const int wh = blockIdx.x;
  uint4 z = make_uint4(0, 0, 0, 0);
  const size_t base = (size_t)wh * 11264 + 10 * 1024;
  for (int i = threadIdx.x; i < 384; i += 256){
    int arr = i >> 7, slot = i & 127;
    unsigned short* p = (arr == 0 ? qs2 : (arr == 1 ? ks2 : vt2));
    *(uint4*)(p + base + slot * 8) = z;
  }
}

// ---------------- tiled weight transpose: out[n][k] = bf16(in[k][n]) ----------------
__global__ __launch_bounds__(256) void wconv2_kernel(const float* __restrict__ in,
                                                     unsigned short* __restrict__ out,
                                                     int K, int N){
  __shared__ unsigned short t[32][33];
  int tx = threadIdx.x & 31, ty = threadIdx.x >> 5;
  int n0 = blockIdx.x * 32, k0 = blockIdx.y * 32;
  #pragma unroll
  for (int i = 0; i < 4; i++)
    t[ty + 8 * i][tx] = f2bf(in[(size_t)(k0 + ty + 8 * i) * N + n0 + tx]);
  __syncthreads();
  #pragma unroll
  for (int i = 0; i < 4; i++)
    out[(size_t)(n0 + ty + 8 * i) * K + k0 + tx] = t[tx][ty + 8 * i];
}

// ---------------- bias prep: bias12[h][q][m] bf16 (pre-scaled by log2e), m>=343 -> -inf-ish ----------------
__global__ void biasprep_kernel(const float* __restrict__ rel, unsigned short* __restrict__ bias12){
  int p = blockIdx.x * 256 + threadIdx.x;
  if (p >= 743424) return;              // 12 * 352 * 176
  int h = p / 61952;
  int rem = p - h * 61952;
  int q = rem / 176;
  int m2 = (rem - q * 176) * 2;
  int qi0 = q / 49, qr = q - qi0 * 49, qi1 = qr / 7, qi2 = qr - qi1 * 7;
  unsigned v[2];
  #pragma unroll
  for (int j = 0; j < 2; j++){
    int m = m2 + j;
    float val;
    if (m >= 343) val = -1.4426950e30f;
    else {
      int mi0 = m / 49, mr = m - mi0 * 49, mi1 = mr / 7, mi2 = mr - mi1 * 7;
      int idx = 13 * (qi0 - mi0 + 6) + (qi1 - mi1 + 6) + (qi2 - mi2);
      if (idx < 0) idx += 2197;
      val = rel[idx * 12 + h] * LOG2E;
    }
    v[j] = f2bf(val);
  }
  *(unsigned*)(&bias12[(size_t)h * 123904 + q * 352 + m2]) = v[0] | (v[1] << 16);
}

// ---------------- mask bitmaps: bitmapG[cls][q][12] u32, bit m set -> add MASKC ----------------
__global__ void maskprep_kernel(unsigned* __restrict__ bitmapG){
  int id = blockIdx.x * 256 + threadIdx.x;
  if (id >= 8 * 352) return;
  int cls = id / 352, q = id - cls * 352;
  int qi0 = q / 49, qr = q - qi0 * 49, qi1 = qr / 7, qi2 = qr - qi1 * 7;
  int az = (cls & 4) ? (qi0 < 4 ? 1 : 2) : 0;
  int ax = (cls & 2) ? (qi1 < 4 ? 1 : 2) : 0;
  int ay = (cls & 1) ? (qi2 < 4 ? 1 : 2) : 0;
  int cq = az * 9 + ax * 3 + ay;
  unsigned w[11];
  #pragma unroll
  for (int t = 0; t < 11; t++) w[t] = 0u;
  for (int m = 0; m < 352; m++){
    int mi0 = m / 49, mr = m - mi0 * 49, mi1 = mr / 7, mi2 = mr - mi1 * 7;
    int bz = (cls & 4) ? (mi0 < 4 ? 1 : 2) : 0;
    int bx = (cls & 2) ? (mi1 < 4 ? 1 : 2) : 0;
    int by = (cls & 1) ? (mi2 < 4 ? 1 : 2) : 0;
    if (bz * 9 + bx * 3 + by != cq) w[m >> 5] |= (1u << (m & 31));
  }
  unsigned* dst = bitmapG + (size_t)id * 12;
  #pragma unroll
  for (int t = 0; t < 11; t++) dst[t] = w[t];
  dst[11] = 0u;
}

// ---------------- LayerNorm (+optional shift+window-partition gather) ----------------
template<int MODE>
__global__ __launch_bounds__(256) void ln_kernel(const float* __restrict__ in,
                                                 const float* __restrict__ g,
                                                 const float* __restrict__ bta,
                                                 unsigned short* __restrict__ out){
  int wave = threadIdx.x >> 6, lane = threadIdx.x & 63;
  int row = blockIdx.x * 4 + wave;          // < 43904
  size_t srow;
  if (MODE == 0){
    int win = row / 343, n = row - win * 343;
    int b = win >> 6, w64 = win & 63;
    int zw = w64 >> 5, xw = (w64 >> 3) & 3, yw = w64 & 7;
    int i0 = n / 49, nr = n - i0 * 49, i1 = nr / 7, i2 = nr - i1 * 7;
    int zs = zw * 7 + i0 + 3; if (zs >= 14) zs -= 14;
    int xs = xw * 7 + i1 + 3; if (xs >= 28) xs -= 28;
    int ys = yw * 7 + i2 + 3; if (ys >= 56) ys -= 56;
    srow = (size_t)b * 21952 + zs * 1568 + xs * 56 + ys;
  } else {
    srow = (size_t)row;
  }
  const float* p = in + srow * 384;
  float v[6]; float s = 0.f;
  #pragma unroll
  for (int i = 0; i < 6; i++){ v[i] = p[lane + i * 64]; s += v[i]; }
  #pragma unroll
  for (int off = 32; off >= 1; off >>= 1) s += __shfl_xor(s, off);
  float mean = s * (1.f / 384.f);
  float vs = 0.f;
  #pragma unroll
  for (int i = 0; i < 6; i++){ float d = v[i] - mean; vs += d * d; }
  #pragma unroll
  for (int off = 32; off >= 1; off >>= 1) vs += __shfl_xor(vs, off);
  float rstd = rsqrtf(vs * (1.f / 384.f) + 1e-5f);
  unsigned short* o = out + (size_t)row * 384;
  #pragma unroll
  for (int i = 0; i < 6; i++){
    int c = lane + i * 64;
    o[c] = f2bf((v[i] - mean) * rstd * g[c] + bta[c]);
  }
}

// ---------------- GEMM (m97 structure): C[M,N] = A[M,K] @ Bt[N,K]^T ----------------
// EPI 0: +bias, write Q/K/V into fragment-packed per-(win,head) arrays (Q scaled by SCALE*log2e)
// EPI 1: +bias, window-reverse+roll scatter, += resid(x), store f32 (PROJ -> x2)
// EPI 2: +bias, exact GELU, store bf16 (FC1 -> hidden)
// EPI 3: +bias, += resid(x2) row-major, store f32 (FC2 -> out)
template<int EPI>
__global__ __launch_bounds__(256, 2) void gemm2(
    const unsigned short* __restrict__ A,
    const unsigned short* __restrict__ Bt,
    const float* __restrict__ bias,
    const float* __restrict__ resid,
    void* __restrict__ outp,
    unsigned short* __restrict__ oq,
    unsigned short* __restrict__ ok,
    unsigned short* __restrict__ ov,
    int K, int ldc){
  __shared__ unsigned short As[4096];
  __shared__ unsigned short Bs[4096];
  const int tid = threadIdx.x, lane = tid & 63, wave = tid >> 6;
  const int r0 = blockIdx.x * 128, c0 = blockIdx.y * 128;
  const int wr = (wave >> 1) * 64, wc = (wave & 1) * 64;
  f32x4 acc[4][4];
  #pragma unroll
  for (int mi = 0; mi < 4; mi++)
    #pragma unroll
    for (int ni = 0; ni < 4; ni++) acc[mi][ni] = f32x4{0.f, 0.f, 0.f, 0.f};

  // staging: 16 chunks of 1KB (A:0-7, B:8-15); lane covers (row = sub*16 + lane/4, chunk = lane&3)
  // source pre-swizzled: LDS slot (row, cp) holds global k-chunk cp ^ ((row>>1)&3)
  const int srow = lane >> 2;
  const int koff = ((lane & 3) ^ ((lane >> 3) & 3)) * 8;
  const int kkey = (lane >> 1) & 3;     // frag-read chunk key (row bits 1-2)

  for (int k0 = 0; k0 < K; k0 += 32){
    __syncthreads();
    #pragma unroll
    for (int i = 0; i < 4; i++){
      int id = wave + i * 4;
      int arr = id >> 3, sub = id & 7;
      const unsigned short* g = (arr ? Bt : A)
          + (size_t)((arr ? c0 : r0) + sub * 16 + srow) * K + k0 + koff;
      unsigned short* dst = (arr ? Bs : As) + sub * 512;
      GLOAD16(g, dst);
    }
    __syncthreads();
    bf16x8 af[4], bfr[4];
    #pragma unroll
    for (int mi = 0; mi < 4; mi++)
      af[mi] = *(const bf16x8*)(&As[(wr + mi * 16 + (lane & 15)) * 32 + (((lane >> 4) ^ kkey) * 8)]);
    #pragma unroll
    for (int ni = 0; ni < 4; ni++)
      bfr[ni] = *(const bf16x8*)(&Bs[(wc + ni * 16 + (lane & 15)) * 32 + (((lane >> 4) ^ kkey) * 8)]);
    #pragma unroll
    for (int mi = 0; mi < 4; mi++)
      #pragma unroll
      for (int ni = 0; ni < 4; ni++)
        acc[mi][ni] = __builtin_amdgcn_mfma_f32_16x16x32_bf16(af[mi], bfr[ni], acc[mi][ni], 0, 0, 0);
  }

  #pragma unroll
  for (int mi = 0; mi < 4; mi++){
    #pragma unroll
    for (int j = 0; j < 4; j++){
      const int row = r0 + wr + mi * 16 + ((lane >> 4) << 2) + j;
      int win, m, t, mloc, vhalf2;
      if (EPI == 0 || EPI == 1){
        win = row / 343; m = row - win * 343;
      }
      if (EPI == 0){
        t = m >> 5; mloc = m & 31;
        vhalf2 = ((m >> 4) & 1) * 512 + ((m >> 3) & 1) * 256 + (m & 7);
      }
      #pragma unroll
      for (int ni = 0; ni < 4; ni++){
        const int col = c0 + wc + ni * 16 + (lane & 15);
        const int r = j;  // acc element index within f32x4
        float val = acc[mi][ni][r] + bias[col];
        if (EPI == 0){
          if (col < 768){
            // Q (col<384, scaled) and K share packing: t*1024 + (dd>>4)*512 + ((dd>>3)&1)*256 + mloc*8 + (dd&7)
            int d = col, dd;
            unsigned short* base;
            if (col < 384){ val *= SL2E; dd = d & 31; base = oq; }
            else { d = col - 384; dd = d & 31; base = ok; }
            int h = d >> 5;
            size_t off = (size_t)(win * 12 + h) * 11264
                       + (size_t)(t * 1024 + ((dd >> 4) & 1) * 512 + ((dd >> 3) & 1) * 256 + mloc * 8 + (dd & 7));
            base[off] = f2bf(val);
          } else {
            int d = col - 768, dd = d & 31, h = d >> 5;
            size_t off = (size_t)(win * 12 + h) * 11264
                       + (size_t)(t * 1024 + vhalf2 + dd * 8);
            ov[off] = f2bf(val);
          }
        } else if (EPI == 1){
          int b = win >> 6, w64 = win & 63;
          int zw = w64 >> 5, xw = (w64 >> 3) & 3, yw = w64 & 7;
          int i0 = m / 49, nr = m - i0 * 49, i1 = nr / 7, i2 = nr - i1 * 7;
          int zf = zw * 7 + i0 + 3; if (zf >= 14) zf -= 14;
          int xf = xw * 7 + i1 + 3; if (xf >= 28) xf -= 28;
          int yf = yw * 7 + i2 + 3; if (yf >= 56) yf -= 56;
          size_t dst = ((size_t)b * 21952 + zf * 1568 + xf * 56 + yf) * 384 + col;
          ((float*)outp)[dst] = resid[dst] + val;
        } else if (EPI == 2){
          val = 0.5f * val * (1.0f + erff(val * 0.70710678118654752f));
          ((unsigned short*)outp)[(size_t)row * ldc + col] = f2bf(val);
        } else {
          ((float*)outp)[(size_t)row * ldc + col] =
              resid[(size_t)row * ldc + col] + val;
        }
      }
    }
  }
}

// ---------------- MFMA attention v3: one block per (window, head), 4 waves ----------------
__global__ __launch_bounds__(256, 4) void attn3_kernel(
    const unsigned short* __restrict__ qs2,
    const unsigned short* __restrict__ ks2,
    const unsigned short* __restrict__ vt2,
    const unsigned short* __restrict__ bias12,
    const unsigned* __restrict__ bitmapG,
    unsigned short* __restrict__ out){
  __shared__ unsigned short Ks[11264];     // 22 KB, chunk-packed (linear copy of ks2[wh])
  __shared__ unsigned short Ps[4][1280];   // per-wave P tile, row stride 40 elems
  const int wh = blockIdx.x;
  const int win = wh / 12, h = wh - win * 12;
  const int tid = threadIdx.x, wave = tid >> 6, lane = tid & 63;
  const int ln = lane & 31, hh = lane >> 5;

  const unsigned short* ksrc = ks2 + (size_t)wh * 11264;
  for (int c = wave; c < 22; c += 4)
    GLOAD16(ksrc + c * 512 + lane * 8, &Ks[c * 512]);

  const int w64 = win & 63;
  const int cls = ((((w64 >> 5) & 1) == 1 ? 4 : 0)) | ((((w64 >> 3) & 3) == 3) ? 2 : 0) | (((w64 & 7) == 7) ? 1 : 0);
  __syncthreads();

  const unsigned short* qbase = qs2 + (size_t)wh * 11264;
  const unsigned short* vbase = vt2 + (size_t)wh * 11264;

  for (int qt = wave; qt < 11; qt += 4){
    const int q_lane = qt * 32 + ln;
    const bf16x8 bq0 = *(const bf16x8*)(qbase + qt * 1024 + hh * 256 + ln * 8);
    const bf16x8 bq1 = *(const bf16x8*)(qbase + qt * 1024 + 512 + hh * 256 + ln * 8);
    const unsigned short* brow = bias12 + ((size_t)h * 352 + q_lane) * 352;
    const unsigned* mrow = bitmapG + (size_t)(cls * 352 + q_lane) * 12;

    f32x16 o = zero16();
    float sum = 0.f;
    // prefetch t=0
    bf16x8 nbv0 = *(const bf16x8*)(vbase + hh * 256 + ln * 8);
    bf16x8 nbv1 = *(const bf16x8*)(vbase + 512 + hh * 256 + ln * 8);
    ushort4 nb0 = *(const ushort4*)(brow + hh * 4);
    ushort4 nb1 = *(const ushort4*)(brow + 8 + hh * 4);
    ushort4 nb2 = *(const ushort4*)(brow + 16 + hh * 4);
    ushort4 nb3 = *(const ushort4*)(brow + 24 + hh * 4);
    unsigned nwm = mrow[0];

    for (int t = 0; t < 11; t++){
      const bf16x8 bv0 = nbv0, bv1 = nbv1;
      const ushort4 cb0 = nb0, cb1 = nb1, cb2 = nb2, cb3 = nb3;
      const unsigned wm = nwm;
      if (t < 10){
        const unsigned short* vnext = vbase + (t + 1) * 1024;
        nbv0 = *(const bf16x8*)(vnext + hh * 256 + ln * 8);
        nbv1 = *(const bf16x8*)(vnext + 512 + hh * 256 + ln * 8);
        const unsigned short* bnext = brow + (t + 1) * 32;
        nb0 = *(const ushort4*)(bnext + hh * 4);
        nb1 = *(const ushort4*)(bnext + 8 + hh * 4);
        nb2 = *(const ushort4*)(bnext + 16 + hh * 4);
        nb3 = *(const ushort4*)(bnext + 24 + hh * 4);
        nwm = mrow[t + 1];
      }
      const bf16x8 ka0 = *(const bf16x8*)(&Ks[t * 1024 + hh * 256 + ln * 8]);
      const bf16x8 ka1 = *(const bf16x8*)(&Ks[t * 1024 + 512 + hh * 256 + ln * 8]);
      f32x16 acc = zero16();
      acc = __builtin_amdgcn_mfma_f32_32x32x16_bf16(ka0, bq0, acc, 0, 0, 0);
      acc = __builtin_amdgcn_mfma_f32_32x32x16_bf16(ka1, bq1, acc, 0, 0, 0);

      const unsigned wsh = wm >> (4 * hh);
      float pv[16];
      unsigned short cbv[16];
      *(ushort4*)(&cbv[0]) = cb0; *(ushort4*)(&cbv[4]) = cb1;
      *(ushort4*)(&cbv[8]) = cb2; *(ushort4*)(&cbv[12]) = cb3;
      #pragma unroll
      for (int g = 0; g < 4; g++){
        #pragma unroll
        for (int i = 0; i < 4; i++){
          const int r = g * 4 + i;
          float s = acc[r] + bf2f(cbv[r]);
          if (cls){
            if (wsh & (1u << (i + 8 * g))) s += MASKC;
          }
          float e = exp2f(s);
          sum += e;
          pv[r] = e;
        }
      }
      #pragma unroll
      for (int g = 0; g < 4; g++){
        uint2 pk;
        pk.x = packbf(pv[4 * g], pv[4 * g + 1]);
        pk.y = packbf(pv[4 * g + 2], pv[4 * g + 3]);
        *(uint2*)(&Ps[wave][ln * 40 + 8 * g + 4 * hh]) = pk;
      }
      const bf16x8 pa0 = *(const bf16x8*)(&Ps[wave][ln * 40 + 8 * hh]);
      const bf16x8 pa1 = *(const bf16x8*)(&Ps[wave][ln * 40 + 16 + 8 * hh]);
      o = __builtin_amdgcn_mfma_f32_32x32x16_bf16(pa0, bv0, o, 0, 0, 0);
      o = __builtin_amdgcn_mfma_f32_32x32x16_bf16(pa1, bv1, o, 0, 0, 0);
    }
    sum += __shfl_xor(sum, 32);
    const float inv = 1.f / sum;   // lane ln holds inv for q-local = ln
    #pragma unroll
    for (int r = 0; r < 16; r++){
      const int qloc = (r & 3) + 8 * (r >> 2) + 4 * hh;
      const float iv = __shfl(inv, qloc);
      const int qg = qt * 32 + qloc;
      if (qg < 343)
        out[((size_t)win * 343 + qg) * 384 + h * 32 + ln] = f2bf(o[r] * iv);
    }
  }
}

// ---------------- host launcher ----------------
extern "C" void kernel_launch(void* const* d_in, const int* in_sizes, int n_in,
                              void* d_out, int out_size, void* d_ws, size_t ws_size,
                              hipStream_t stream){
  const float* x      = (const float*)d_in[0];
  const float* n1g    = (const float*)d_in[1];
  const float* n1b    = (const float*)d_in[2];
  const float* qkv_w  = (const float*)d_in[3];
  const float* qkv_b  = (const float*)d_in[4];
  const float* proj_w = (const float*)d_in[5];
  const float* proj_b = (const float*)d_in[6];
  const float* rel    = (const float*)d_in[7];
  const float* n2g    = (const float*)d_in[8];
  const float* n2b    = (const float*)d_in[9];
  const float* fc1_w  = (const float*)d_in[10];
  const float* fc1_b  = (const float*)d_in[11];
  const float* fc2_w  = (const float*)d_in[12];
  const float* fc2_b  = (const float*)d_in[13];
  float* out = (float*)d_out;

  char* ws = (char*)d_ws;
  // Region plan (bytes), high-water 239,566,848:
  // [0, 33.7M)            w_win bf16 [43904][384]      -- reused as hidden bf16 [43904][1536] (0..134.9M)
  // [33.7M, 68.3M)        qs2   (frag-packed Q)        -- dead after attn
  // [68.3M, 102.9M)       ks2                          -- dead after attn
  // [102.9M, 137.5M)      vt2                          -- dead after attn
  // [134.9M, 202.3M)      x2 f32 (written post-attn); pre-attn holds bias12+bitmap @137.5M
  // [202.3M, 236.0M)      att bf16 -- reused as ln2
  // [236.0M, 239.6M)      bf16 transposed weights
  // All attn-read regions (incl. qs2/ks2/vt2 pads) are rewritten EVERY call
  // (padzero + gemm2<0>) -> no cross-call state dependence.
  unsigned short* w_win  = (unsigned short*)(ws + 0);
  unsigned short* hidden = (unsigned short*)(ws + 0);
  unsigned short* qs2    = (unsigned short*)(ws + 33718272ull);
  unsigned short* ks2    = (unsigned short*)(ws + 68321280ull);
  unsigned short* vt2    = (unsigned short*)(ws + 102924288ull);
  float*          x2     = (float*)(ws + 134873088ull);
  unsigned short* bias12 = (unsigned short*)(ws + 137527296ull);
  unsigned*       bitmapG= (unsigned*)(ws + 140504064ull);
  unsigned short* att    = (unsigned short*)(ws + 202309632ull);
  unsigned short* ln2    = att;
  unsigned short* wt_qkv = (unsigned short*)(ws + 236027904ull);
  unsigned short* wt_prj = (unsigned short*)(ws + 236912640ull);
  unsigned short* wt_fc1 = (unsigned short*)(ws + 237207552ull);
  unsigned short* wt_fc2 = (unsigned short*)(ws + 238387200ull);

  wconv2_kernel<<<dim3(36, 12), 256, 0, stream>>>(qkv_w, wt_qkv, 384, 1152);
  wconv2_kernel<<<dim3(12, 12), 256, 0, stream>>>(proj_w, wt_prj, 384, 384);
  wconv2_kernel<<<dim3(48, 12), 256, 0, stream>>>(fc1_w, wt_fc1, 384, 1536);
  wconv2_kernel<<<dim3(12, 48), 256, 0, stream>>>(fc2_w, wt_fc2, 1536, 384);
  biasprep_kernel<<<2904, 256, 0, stream>>>(rel, bias12);
  maskprep_kernel<<<11, 256, 0, stream>>>(bitmapG);
  padzero_kernel<<<1536, 256, 0, stream>>>(qs2, ks2, vt2);

  ln_kernel<0><<<10976, 256, 0, stream>>>(x, n1g, n1b, w_win);
  gemm2<0><<<dim3(343, 9), 256, 0, stream>>>(w_win, wt_qkv, qkv_b, nullptr, nullptr,
                                             qs2, ks2, vt2, 384, 0);
  attn3_kernel<<<1536, 256, 0, stream>>>(qs2, ks2, vt2, bias12, bitmapG, att);
  gemm2<1><<<dim3(343, 3), 256, 0, stream>>>(att, wt_prj, proj_b, x, x2,
                                             nullptr, nullptr, nullptr, 384, 384);
  ln_kernel<1><<<10976, 256, 0, stream>>>(x2, n2g, n2b, ln2);
  gemm2<2><<<dim3(343, 12), 256, 0, stream>>>(ln2, wt_fc1, fc1_b, nullptr, hidden,
                                              nullptr, nullptr, nullptr, 384, 1536);
  gemm2<3><<<dim3(343, 3), 256, 0, stream>>>(hidden, wt_fc2, fc2_b, x2, out,
                                             nullptr, nullptr, nullptr, 1536, 384);
}

// Round 5
// 529.714 us; speedup vs baseline: 5.3966x; 1.0579x over previous
//
#include <hip/hip_runtime.h>
#include <hip/hip_bf16.h>
#include <cmath>

typedef float f32x4 __attribute__((ext_vector_type(4)));
typedef float f32x16 __attribute__((ext_vector_type(16)));
typedef short bf16x8 __attribute__((ext_vector_type(8)));
typedef const __attribute__((address_space(1))) unsigned int* gas_t;
typedef __attribute__((address_space(3))) unsigned int* las_t;

#define GLOAD16(g, l) __builtin_amdgcn_global_load_lds((gas_t)(const void*)(g), (las_t)(void*)(l), 16, 0, 0)

#define LOG2E 1.4426950408889634f
#define MASKC (-144.2695040888963f)
#define SL2E  (0.17677669529663687f * 1.4426950408889634f)

static __device__ __forceinline__ float bf2f(unsigned short u){
  return __uint_as_float(((unsigned)u) << 16);
}
static __device__ __forceinline__ unsigned short f2bf(float f){
  unsigned u = __float_as_uint(f);
  unsigned r = u + 0x7FFFu + ((u >> 16) & 1u);
  return (unsigned short)(r >> 16);
}
static __device__ __forceinline__ unsigned packbf(float a, float b){
  union { __hip_bfloat162 h; unsigned u; } cv;
  cv.h = __float22bfloat162_rn(make_float2(a, b));
  return cv.u;
}
static __device__ __forceinline__ f32x16 zero16(){
  f32x16 z;
  #pragma unroll
  for (int i = 0; i < 16; i++) z[i] = 0.f;
  return z;
}

// ---------------- zero pad slots (tile t=10) of qs2/ks2/vt2 ----------------
__global__ __launch_bounds__(256) void padzero_kernel(unsigned short* __restrict__ qs2,
                                                      unsigned short* __restrict__ ks2,
                                                      unsigned short* __restrict__ vt2){
  const int wh = blockIdx.x;
  uint4 z = make_uint4(0, 0, 0, 0);
  const size_t base = (size_t)wh * 11264 + 10 * 1024;
  for (int i = threadIdx.x; i < 384; i += 256){
    int arr = i >> 7, slot = i & 127;
    unsigned short* p = (arr == 0 ? qs2 : (arr == 1 ? ks2 : vt2));
    *(uint4*)(p + base + slot * 8) = z;
  }
}

// ---------------- tiled weight transpose: out[n][k] = bf16(in[k][n]) ----------------
__global__ __launch_bounds__(256) void wconv2_kernel(const float* __restrict__ in,
                                                     unsigned short* __restrict__ out,
                                                     int K, int N){
  __shared__ unsigned short t[32][33];
  int tx = threadIdx.x & 31, ty = threadIdx.x >> 5;
  int n0 = blockIdx.x * 32, k0 = blockIdx.y * 32;
  #pragma unroll
  for (int i = 0; i < 4; i++)
    t[ty + 8 * i][tx] = f2bf(in[(size_t)(k0 + ty + 8 * i) * N + n0 + tx]);
  __syncthreads();
  #pragma unroll
  for (int i = 0; i < 4; i++)
    out[(size_t)(n0 + ty + 8 * i) * K + k0 + tx] = t[tx][ty + 8 * i];
}

// ---------------- bias prep: bias12[h][q][m] bf16 (pre-scaled by log2e), m>=343 -> -inf-ish ----------------
__global__ void biasprep_kernel(const float* __restrict__ rel, unsigned short* __restrict__ bias12){
  int p = blockIdx.x * 256 + threadIdx.x;
  if (p >= 743424) return;              // 12 * 352 * 176
  int h = p / 61952;
  int rem = p - h * 61952;
  int q = rem / 176;
  int m2 = (rem - q * 176) * 2;
  int qi0 = q / 49, qr = q - qi0 * 49, qi1 = qr / 7, qi2 = qr - qi1 * 7;
  unsigned v[2];
  #pragma unroll
  for (int j = 0; j < 2; j++){
    int m = m2 + j;
    float val;
    if (m >= 343) val = -1.4426950e30f;
    else {
      int mi0 = m / 49, mr = m - mi0 * 49, mi1 = mr / 7, mi2 = mr - mi1 * 7;
      int idx = 13 * (qi0 - mi0 + 6) + (qi1 - mi1 + 6) + (qi2 - mi2);
      if (idx < 0) idx += 2197;
      val = rel[idx * 12 + h] * LOG2E;
    }
    v[j] = f2bf(val);
  }
  *(unsigned*)(&bias12[(size_t)h * 123904 + q * 352 + m2]) = v[0] | (v[1] << 16);
}

// ---------------- mask bitmaps: bitmapG[cls][q][12] u32, bit m set -> add MASKC ----------------
__global__ void maskprep_kernel(unsigned* __restrict__ bitmapG){
  int id = blockIdx.x * 256 + threadIdx.x;
  if (id >= 8 * 352) return;
  int cls = id / 352, q = id - cls * 352;
  int qi0 = q / 49, qr = q - qi0 * 49, qi1 = qr / 7, qi2 = qr - qi1 * 7;
  int az = (cls & 4) ? (qi0 < 4 ? 1 : 2) : 0;
  int ax = (cls & 2) ? (qi1 < 4 ? 1 : 2) : 0;
  int ay = (cls & 1) ? (qi2 < 4 ? 1 : 2) : 0;
  int cq = az * 9 + ax * 3 + ay;
  unsigned w[11];
  #pragma unroll
  for (int t = 0; t < 11; t++) w[t] = 0u;
  for (int m = 0; m < 352; m++){
    int mi0 = m / 49, mr = m - mi0 * 49, mi1 = mr / 7, mi2 = mr - mi1 * 7;
    int bz = (cls & 4) ? (mi0 < 4 ? 1 : 2) : 0;
    int bx = (cls & 2) ? (mi1 < 4 ? 1 : 2) : 0;
    int by = (cls & 1) ? (mi2 < 4 ? 1 : 2) : 0;
    if (bz * 9 + bx * 3 + by != cq) w[m >> 5] |= (1u << (m & 31));
  }
  unsigned* dst = bitmapG + (size_t)id * 12;
  #pragma unroll
  for (int t = 0; t < 11; t++) dst[t] = w[t];
  dst[11] = 0u;
}

// ---------------- LayerNorm (+optional shift+window-partition gather) ----------------
template<int MODE>
__global__ __launch_bounds__(256) void ln_kernel(const float* __restrict__ in,
                                                 const float* __restrict__ g,
                                                 const float* __restrict__ bta,
                                                 unsigned short* __restrict__ out){
  int wave = threadIdx.x >> 6, lane = threadIdx.x & 63;
  int row = blockIdx.x * 4 + wave;          // < 43904
  size_t srow;
  if (MODE == 0){
    int win = row / 343, n = row - win * 343;
    int b = win >> 6, w64 = win & 63;
    int zw = w64 >> 5, xw = (w64 >> 3) & 3, yw = w64 & 7;
    int i0 = n / 49, nr = n - i0 * 49, i1 = nr / 7, i2 = nr - i1 * 7;
    int zs = zw * 7 + i0 + 3; if (zs >= 14) zs -= 14;
    int xs = xw * 7 + i1 + 3; if (xs >= 28) xs -= 28;
    int ys = yw * 7 + i2 + 3; if (ys >= 56) ys -= 56;
    srow = (size_t)b * 21952 + zs * 1568 + xs * 56 + ys;
  } else {
    srow = (size_t)row;
  }
  const float* p = in + srow * 384;
  float v[6]; float s = 0.f;
  #pragma unroll
  for (int i = 0; i < 6; i++){ v[i] = p[lane + i * 64]; s += v[i]; }
  #pragma unroll
  for (int off = 32; off >= 1; off >>= 1) s += __shfl_xor(s, off);
  float mean = s * (1.f / 384.f);
  float vs = 0.f;
  #pragma unroll
  for (int i = 0; i < 6; i++){ float d = v[i] - mean; vs += d * d; }
  #pragma unroll
  for (int off = 32; off >= 1; off >>= 1) vs += __shfl_xor(vs, off);
  float rstd = rsqrtf(vs * (1.f / 384.f) + 1e-5f);
  unsigned short* o = out + (size_t)row * 384;
  #pragma unroll
  for (int i = 0; i < 6; i++){
    int c = lane + i * 64;
    o[c] = f2bf((v[i] - mean) * rstd * g[c] + bta[c]);
  }
}

// ---------------- GEMM (m97 structure): C[M,N] = A[M,K] @ Bt[N,K]^T ----------------
// 1D grid, N-tile fastest within an M-panel + bijective XCD chunk swizzle:
// consecutive blocks on one XCD share the A-panel (L2-resident) -> A fetched from HBM once.
template<int EPI>
__global__ __launch_bounds__(256, 2) void gemm2(
    const unsigned short* __restrict__ A,
    const unsigned short* __restrict__ Bt,
    const float* __restrict__ bias,
    const float* __restrict__ resid,
    void* __restrict__ outp,
    unsigned short* __restrict__ oq,
    unsigned short* __restrict__ ok,
    unsigned short* __restrict__ ov,
    int K, int ldc, int nt){
  __shared__ unsigned short As[4096];
  __shared__ unsigned short Bs[4096];
  // ---- bijective XCD swizzle (m204): XCD x owns a contiguous wgid chunk ----
  const int nwg = gridDim.x;
  const int qq = nwg >> 3, rr = nwg & 7;
  const int xcd = blockIdx.x & 7, pos = blockIdx.x >> 3;
  const int wgid = (xcd < rr ? xcd * (qq + 1) : rr * (qq + 1) + (xcd - rr) * qq) + pos;
  const int mtile = wgid / nt, ntile = wgid - mtile * nt;
  const int r0 = mtile * 128, c0 = ntile * 128;

  const int tid = threadIdx.x, lane = tid & 63, wave = tid >> 6;
  const int wr = (wave >> 1) * 64, wc = (wave & 1) * 64;
  f32x4 acc[4][4];
  #pragma unroll
  for (int mi = 0; mi < 4; mi++)
    #pragma unroll
    for (int ni = 0; ni < 4; ni++) acc[mi][ni] = f32x4{0.f, 0.f, 0.f, 0.f};

  // staging: 16 chunks of 1KB (A:0-7, B:8-15); lane covers (row = sub*16 + lane/4, chunk = lane&3)
  // source pre-swizzled: LDS slot (row, cp) holds global k-chunk cp ^ ((row>>1)&3)
  const int srow = lane >> 2;
  const int koff = ((lane & 3) ^ ((lane >> 3) & 3)) * 8;
  const int kkey = (lane >> 1) & 3;     // frag-read chunk key (row bits 1-2)

  for (int k0 = 0; k0 < K; k0 += 32){
    __syncthreads();
    #pragma unroll
    for (int i = 0; i < 4; i++){
      int id = wave + i * 4;
      int arr = id >> 3, sub = id & 7;
      const unsigned short* g = (arr ? Bt : A)
          + (size_t)((arr ? c0 : r0) + sub * 16 + srow) * K + k0 + koff;
      unsigned short* dst = (arr ? Bs : As) + sub * 512;
      GLOAD16(g, dst);
    }
    __syncthreads();
    bf16x8 af[4], bfr[4];
    #pragma unroll
    for (int mi = 0; mi < 4; mi++)
      af[mi] = *(const bf16x8*)(&As[(wr + mi * 16 + (lane & 15)) * 32 + (((lane >> 4) ^ kkey) * 8)]);
    #pragma unroll
    for (int ni = 0; ni < 4; ni++)
      bfr[ni] = *(const bf16x8*)(&Bs[(wc + ni * 16 + (lane & 15)) * 32 + (((lane >> 4) ^ kkey) * 8)]);
    #pragma unroll
    for (int mi = 0; mi < 4; mi++)
      #pragma unroll
      for (int ni = 0; ni < 4; ni++)
        acc[mi][ni] = __builtin_amdgcn_mfma_f32_16x16x32_bf16(af[mi], bfr[ni], acc[mi][ni], 0, 0, 0);
  }

  #pragma unroll
  for (int mi = 0; mi < 4; mi++){
    #pragma unroll
    for (int j = 0; j < 4; j++){
      const int row = r0 + wr + mi * 16 + ((lane >> 4) << 2) + j;
      int win, m, t, mloc, vhalf2;
      if (EPI == 0 || EPI == 1){
        win = row / 343; m = row - win * 343;
      }
      if (EPI == 0){
        t = m >> 5; mloc = m & 31;
        vhalf2 = ((m >> 4) & 1) * 512 + ((m >> 3) & 1) * 256 + (m & 7);
      }
      #pragma unroll
      for (int ni = 0; ni < 4; ni++){
        const int col = c0 + wc + ni * 16 + (lane & 15);
        const int r = j;  // acc element index within f32x4
        float val = acc[mi][ni][r] + bias[col];
        if (EPI == 0){
          if (col < 768){
            // Q (col<384, scaled) and K share packing: t*1024 + (dd>>4)*512 + ((dd>>3)&1)*256 + mloc*8 + (dd&7)
            int d = col, dd;
            unsigned short* base;
            if (col < 384){ val *= SL2E; dd = d & 31; base = oq; }
            else { d = col - 384; dd = d & 31; base = ok; }
            int h = d >> 5;
            size_t off = (size_t)(win * 12 + h) * 11264
                       + (size_t)(t * 1024 + ((dd >> 4) & 1) * 512 + ((dd >> 3) & 1) * 256 + mloc * 8 + (dd & 7));
            base[off] = f2bf(val);
          } else {
            int d = col - 768, dd = d & 31, h = d >> 5;
            size_t off = (size_t)(win * 12 + h) * 11264
                       + (size_t)(t * 1024 + vhalf2 + dd * 8);
            ov[off] = f2bf(val);
          }
        } else if (EPI == 1){
          int b = win >> 6, w64 = win & 63;
          int zw = w64 >> 5, xw = (w64 >> 3) & 3, yw = w64 & 7;
          int i0 = m / 49, nr = m - i0 * 49, i1 = nr / 7, i2 = nr - i1 * 7;
          int zf = zw * 7 + i0 + 3; if (zf >= 14) zf -= 14;
          int xf = xw * 7 + i1 + 3; if (xf >= 28) xf -= 28;
          int yf = yw * 7 + i2 + 3; if (yf >= 56) yf -= 56;
          size_t dst = ((size_t)b * 21952 + zf * 1568 + xf * 56 + yf) * 384 + col;
          ((float*)outp)[dst] = resid[dst] + val;
        } else if (EPI == 2){
          val = 0.5f * val * (1.0f + erff(val * 0.70710678118654752f));
          ((unsigned short*)outp)[(size_t)row * ldc + col] = f2bf(val);
        } else {
          ((float*)outp)[(size_t)row * ldc + col] =
              resid[(size_t)row * ldc + col] + val;
        }
      }
    }
  }
}

// ---------------- MFMA attention v3: one block per (window, head), 4 waves ----------------
__global__ __launch_bounds__(256, 4) void attn3_kernel(
    const unsigned short* __restrict__ qs2,
    const unsigned short* __restrict__ ks2,
    const unsigned short* __restrict__ vt2,
    const unsigned short* __restrict__ bias12,
    const unsigned* __restrict__ bitmapG,
    unsigned short* __restrict__ out){
  __shared__ unsigned short Ks[11264];     // 22 KB, chunk-packed (linear copy of ks2[wh])
  __shared__ unsigned short Ps[4][1280];   // per-wave P tile, row stride 40 elems
  const int wh = blockIdx.x;
  const int win = wh / 12, h = wh - win * 12;
  const int tid = threadIdx.x, wave = tid >> 6, lane = tid & 63;
  const int ln = lane & 31, hh = lane >> 5;

  const unsigned short* ksrc = ks2 + (size_t)wh * 11264;
  for (int c = wave; c < 22; c += 4)
    GLOAD16(ksrc + c * 512 + lane * 8, &Ks[c * 512]);

  const int w64 = win & 63;
  const int cls = ((((w64 >> 5) & 1) == 1 ? 4 : 0)) | ((((w64 >> 3) & 3) == 3) ? 2 : 0) | (((w64 & 7) == 7) ? 1 : 0);
  __syncthreads();

  const unsigned short* qbase = qs2 + (size_t)wh * 11264;
  const unsigned short* vbase = vt2 + (size_t)wh * 11264;

  for (int qt = wave; qt < 11; qt += 4){
    const int q_lane = qt * 32 + ln;
    const bf16x8 bq0 = *(const bf16x8*)(qbase + qt * 1024 + hh * 256 + ln * 8);
    const bf16x8 bq1 = *(const bf16x8*)(qbase + qt * 1024 + 512 + hh * 256 + ln * 8);
    const unsigned short* brow = bias12 + ((size_t)h * 352 + q_lane) * 352;
    const unsigned* mrow = bitmapG + (size_t)(cls * 352 + q_lane) * 12;

    f32x16 o = zero16();
    float sum = 0.f;
    // prefetch t=0
    bf16x8 nbv0 = *(const bf16x8*)(vbase + hh * 256 + ln * 8);
    bf16x8 nbv1 = *(const bf16x8*)(vbase + 512 + hh * 256 + ln * 8);
    ushort4 nb0 = *(const ushort4*)(brow + hh * 4);
    ushort4 nb1 = *(const ushort4*)(brow + 8 + hh * 4);
    ushort4 nb2 = *(const ushort4*)(brow + 16 + hh * 4);
    ushort4 nb3 = *(const ushort4*)(brow + 24 + hh * 4);
    unsigned nwm = mrow[0];

    for (int t = 0; t < 11; t++){
      const bf16x8 bv0 = nbv0, bv1 = nbv1;
      const ushort4 cb0 = nb0, cb1 = nb1, cb2 = nb2, cb3 = nb3;
      const unsigned wm = nwm;
      if (t < 10){
        const unsigned short* vnext = vbase + (t + 1) * 1024;
        nbv0 = *(const bf16x8*)(vnext + hh * 256 + ln * 8);
        nbv1 = *(const bf16x8*)(vnext + 512 + hh * 256 + ln * 8);
        const unsigned short* bnext = brow + (t + 1) * 32;
        nb0 = *(const ushort4*)(bnext + hh * 4);
        nb1 = *(const ushort4*)(bnext + 8 + hh * 4);
        nb2 = *(const ushort4*)(bnext + 16 + hh * 4);
        nb3 = *(const ushort4*)(bnext + 24 + hh * 4);
        nwm = mrow[t + 1];
      }
      const bf16x8 ka0 = *(const bf16x8*)(&Ks[t * 1024 + hh * 256 + ln * 8]);
      const bf16x8 ka1 = *(const bf16x8*)(&Ks[t * 1024 + 512 + hh * 256 + ln * 8]);
      f32x16 acc = zero16();
      acc = __builtin_amdgcn_mfma_f32_32x32x16_bf16(ka0, bq0, acc, 0, 0, 0);
      acc = __builtin_amdgcn_mfma_f32_32x32x16_bf16(ka1, bq1, acc, 0, 0, 0);

      const unsigned wsh = wm >> (4 * hh);
      float pv[16];
      unsigned short cbv[16];
      *(ushort4*)(&cbv[0]) = cb0; *(ushort4*)(&cbv[4]) = cb1;
      *(ushort4*)(&cbv[8]) = cb2; *(ushort4*)(&cbv[12]) = cb3;
      #pragma unroll
      for (int g = 0; g < 4; g++){
        #pragma unroll
        for (int i = 0; i < 4; i++){
          const int r = g * 4 + i;
          float s = acc[r] + bf2f(cbv[r]);
          if (cls){
            if (wsh & (1u << (i + 8 * g))) s += MASKC;
          }
          float e = exp2f(s);
          sum += e;
          pv[r] = e;
        }
      }
      #pragma unroll
      for (int g = 0; g < 4; g++){
        uint2 pk;
        pk.x = packbf(pv[4 * g], pv[4 * g + 1]);
        pk.y = packbf(pv[4 * g + 2], pv[4 * g + 3]);
        *(uint2*)(&Ps[wave][ln * 40 + 8 * g + 4 * hh]) = pk;
      }
      const bf16x8 pa0 = *(const bf16x8*)(&Ps[wave][ln * 40 + 8 * hh]);
      const bf16x8 pa1 = *(const bf16x8*)(&Ps[wave][ln * 40 + 16 + 8 * hh]);
      o = __builtin_amdgcn_mfma_f32_32x32x16_bf16(pa0, bv0, o, 0, 0, 0);
      o = __builtin_amdgcn_mfma_f32_32x32x16_bf16(pa1, bv1, o, 0, 0, 0);
    }
    sum += __shfl_xor(sum, 32);
    const float inv = 1.f / sum;   // lane ln holds inv for q-local = ln
    #pragma unroll
    for (int r = 0; r < 16; r++){
      const int qloc = (r & 3) + 8 * (r >> 2) + 4 * hh;
      const float iv = __shfl(inv, qloc);
      const int qg = qt * 32 + qloc;
      if (qg < 343)
        out[((size_t)win * 343 + qg) * 384 + h * 32 + ln] = f2bf(o[r] * iv);
    }
  }
}

// ---------------- host launcher ----------------
extern "C" void kernel_launch(void* const* d_in, const int* in_sizes, int n_in,
                              void* d_out, int out_size, void* d_ws, size_t ws_size,
                              hipStream_t stream){
  const float* x      = (const float*)d_in[0];
  const float* n1g    = (const float*)d_in[1];
  const float* n1b    = (const float*)d_in[2];
  const float* qkv_w  = (const float*)d_in[3];
  const float* qkv_b  = (const float*)d_in[4];
  const float* proj_w = (const float*)d_in[5];
  const float* proj_b = (const float*)d_in[6];
  const float* rel    = (const float*)d_in[7];
  const float* n2g    = (const float*)d_in[8];
  const float* n2b    = (const float*)d_in[9];
  const float* fc1_w  = (const float*)d_in[10];
  const float* fc1_b  = (const float*)d_in[11];
  const float* fc2_w  = (const float*)d_in[12];
  const float* fc2_b  = (const float*)d_in[13];
  float* out = (float*)d_out;

  char* ws = (char*)d_ws;
  // Region plan (bytes), high-water 239,566,848:
  // [0, 33.7M)            w_win bf16 [43904][384]      -- reused as hidden bf16 [43904][1536] (0..134.9M)
  // [33.7M, 68.3M)        qs2   (frag-packed Q)        -- dead after attn
  // [68.3M, 102.9M)       ks2                          -- dead after attn
  // [102.9M, 137.5M)      vt2                          -- dead after attn
  // [134.9M, 202.3M)      x2 f32 (written post-attn); pre-attn holds bias12+bitmap @137.5M
  // [202.3M, 236.0M)      att bf16 -- reused as ln2
  // [236.0M, 239.6M)      bf16 transposed weights
  // All attn-read regions (incl. qs2/ks2/vt2 pads) are rewritten EVERY call.
  unsigned short* w_win  = (unsigned short*)(ws + 0);
  unsigned short* hidden = (unsigned short*)(ws + 0);
  unsigned short* qs2    = (unsigned short*)(ws + 33718272ull);
  unsigned short* ks2    = (unsigned short*)(ws + 68321280ull);
  unsigned short* vt2    = (unsigned short*)(ws + 102924288ull);
  float*          x2     = (float*)(ws + 134873088ull);
  unsigned short* bias12 = (unsigned short*)(ws + 137527296ull);
  unsigned*       bitmapG= (unsigned*)(ws + 140504064ull);
  unsigned short* att    = (unsigned short*)(ws + 202309632ull);
  unsigned short* ln2    = att;
  unsigned short* wt_qkv = (unsigned short*)(ws + 236027904ull);
  unsigned short* wt_prj = (unsigned short*)(ws + 236912640ull);
  unsigned short* wt_fc1 = (unsigned short*)(ws + 237207552ull);
  unsigned short* wt_fc2 = (unsigned short*)(ws + 238387200ull);

  wconv2_kernel<<<dim3(36, 12), 256, 0, stream>>>(qkv_w, wt_qkv, 384, 1152);
  wconv2_kernel<<<dim3(12, 12), 256, 0, stream>>>(proj_w, wt_prj, 384, 384);
  wconv2_kernel<<<dim3(48, 12), 256, 0, stream>>>(fc1_w, wt_fc1, 384, 1536);
  wconv2_kernel<<<dim3(12, 48), 256, 0, stream>>>(fc2_w, wt_fc2, 1536, 384);
  biasprep_kernel<<<2904, 256, 0, stream>>>(rel, bias12);
  maskprep_kernel<<<11, 256, 0, stream>>>(bitmapG);
  padzero_kernel<<<1536, 256, 0, stream>>>(qs2, ks2, vt2);

  ln_kernel<0><<<10976, 256, 0, stream>>>(x, n1g, n1b, w_win);
  gemm2<0><<<343 * 9, 256, 0, stream>>>(w_win, wt_qkv, qkv_b, nullptr, nullptr,
                                        qs2, ks2, vt2, 384, 0, 9);
  attn3_kernel<<<1536, 256, 0, stream>>>(qs2, ks2, vt2, bias12, bitmapG, att);
  gemm2<1><<<343 * 3, 256, 0, stream>>>(att, wt_prj, proj_b, x, x2,
                                        nullptr, nullptr, nullptr, 384, 384, 3);
  ln_kernel<1><<<10976, 256, 0, stream>>>(x2, n2g, n2b, ln2);
  gemm2<2><<<343 * 12, 256, 0, stream>>>(ln2, wt_fc1, fc1_b, nullptr, hidden,
                                         nullptr, nullptr, nullptr, 384, 1536, 12);
  gemm2<3><<<343 * 3, 256, 0, stream>>>(hidden, wt_fc2, fc2_b, x2, out,
                                        nullptr, nullptr, nullptr, 1536, 384, 3);
}